// Round 4
// baseline (226.077 us; speedup 1.0000x reference)
//
#include <hip/hip_runtime.h>
#include <stdint.h>
#include <stddef.h>

#define D_MODEL 1024
#define D_STATE 16
#define D_INNER 2048
#define BATCH   2
#define SEQ     1024
#define MROWS   (BATCH*SEQ)   // 2048

// chunked scan config (R8: NCH=32 + state-split x2 -> 16 waves/CU, scanC 44->~15us)
#define NCH 32
#define TCH (SEQ/NCH)         // 32
#define NREC (BATCH*D_INNER*D_STATE)  // 65536
#define DPB 128               // channels per scan block (256 thr / 2 halves)

typedef __bf16 bf16x8 __attribute__((ext_vector_type(8)));
typedef float  f32x4  __attribute__((ext_vector_type(4)));
typedef unsigned short u16x8 __attribute__((ext_vector_type(8)));

__device__ __forceinline__ unsigned short f2bf(float f) {
    unsigned int u = __float_as_uint(f);
    u += 0x7fffu + ((u >> 16) & 1u);      // RNE
    return (unsigned short)(u >> 16);
}
__device__ __forceinline__ float bf2f(unsigned short v) {
    return __uint_as_float((unsigned int)v << 16);
}

// async global -> LDS, 16B/lane. Global addr is PER-LANE (gather); LDS dest is
// wave-uniform base + lane*16 (m104/m108).
__device__ __forceinline__ void gl_lds16(const unsigned short* g, unsigned short* l) {
    __builtin_amdgcn_global_load_lds(
        (const __attribute__((address_space(1))) unsigned int*)g,
        (__attribute__((address_space(3))) unsigned int*)l, 16, 0, 0);
}

// ---------------- fused fp32 -> bf16 conversions -------------------------------
__global__ void cvt_all_kernel(const float* __restrict__ x,
                               const float* __restrict__ w1,
                               const float* __restrict__ w2,
                               const float* __restrict__ xw,
                               unsigned short* __restrict__ xb,
                               unsigned short* __restrict__ wbi,
                               unsigned short* __restrict__ wbo,
                               unsigned short* __restrict__ wbp) {
    int blk = blockIdx.x, tid = threadIdx.x;
    if (blk < 8192) {
        const float* src; unsigned short* dst; int i;
        if (blk < 2048)      { src = x;  dst = xb;  i = blk * 1024 + tid * 4; }
        else if (blk < 6144) { src = w1; dst = wbi; i = (blk - 2048) * 1024 + tid * 4; }
        else                 { src = w2; dst = wbo; i = (blk - 6144) * 1024 + tid * 4; }
        float4 v = *(const float4*)(src + i);
        ushort4 o;
        o.x = f2bf(v.x); o.y = f2bf(v.y); o.z = f2bf(v.z); o.w = f2bf(v.w);
        *(ushort4*)(dst + i) = o;
    } else {
        int id = (blk - 8192) * 256 + tid;          // 0..65535
        wbp[id] = (id < 17 * D_INNER) ? f2bf(xw[id]) : (unsigned short)0;
    }
}

// ---------------- bf16 MFMA GEMM, BK=64 dual-panel LDS -------------------------
// C[m,n] = sum_k A[m,k]*Bw[n,k]. Tile 128 x NT, 256 thr (4 waves 2x2).
// LDS per buffer = two stride-32 panels per operand (k-half-major).
// R9 (T4 counted-vmcnt graft): raw s_barrier (NOT __syncthreads, which compiles
// to s_waitcnt vmcnt(0)+barrier and drains the prefetch). Each wave issues
// LPW gl_lds per stage; before reading buf[cur] it waits vmcnt(LPW) — only the
// OLDER batch (cur's loads) must have retired; the newest LPW (next tile) stay
// in flight across the barrier (m218: counted-vs-drain0 = +38%).
// Hazards: (1) reads gated by per-wave vmcnt(LPW) BEFORE barrier -> all waves'
// cur-batch LDS writes complete (vmcnt retirement = LDS write done, m135);
// (2) stage(t+2) overwrites buf[cur] only after end-of-iter barrier, by which
// time every wave's MFMAs consumed its ds_reads (lgkmcnt dep); (3) tail waits
// vmcnt(0). sched_barrier(0) pins asm/barrier ordering (rule #18).
// SPLITK2: gridDim.z==2, each z does K/2, C holds partials [z][M][N].
template<int NT, bool SPLITK2, bool OUT_BF16>
__global__ void gemm_bf16_kernel(const unsigned short* __restrict__ A,
                                 const unsigned short* __restrict__ Bw,
                                 void* __restrict__ Cv,
                                 int M, int N, int K) {
    constexpr int NTW = NT / 32;                 // n-frags per wave (4 or 2)
    constexpr int BCH = NT / 8;                  // B chunks per k-iter (16 or 8)
    constexpr int LPW = 4 + BCH / 4;             // gl_lds per wave per stage (8 or 6)
    __shared__ __align__(16) unsigned short Al[2][2 * 128 * 32];   // 2 x 16 KB
    __shared__ __align__(16) unsigned short Bl[2][2 * NT * 32];

    const int tid  = threadIdx.x;
    const int lane = tid & 63;
    const int wid  = tid >> 6;
    const int wm   = wid >> 1;
    const int wn   = wid & 1;
    const int ln   = lane & 15;
    const int q    = lane >> 4;
    const int mblk = blockIdx.y * 128;
    const int nblk = blockIdx.x * NT;
    const int srow = lane >> 2;                  // 0..15 rows within chunk
    const int spart = lane & 3;                  // 16B part within 64B k-half

    const int kbeg = SPLITK2 ? blockIdx.z * (K / 2) : 0;
    const int kend = SPLITK2 ? kbeg + K / 2 : K;

    f32x4 acc[4][NTW] = {};

    auto stage = [&](int buf, int k0) {
        #pragma unroll
        for (int h = 0; h < 4; ++h) {
            int j = wid * 4 + h;
            int kh = j & 1, rb = j >> 1;
            int row = rb * 16 + srow;
            gl_lds16(A + (size_t)(mblk + row) * K + k0 + kh * 32 + spart * 8,
                     Al[buf] + kh * 4096 + rb * 512);
        }
        #pragma unroll
        for (int h = 0; h < BCH / 4; ++h) {
            int j = wid * (BCH / 4) + h;
            int kh = j & 1, rb = j >> 1;         // rb in [0, NT/16)
            int row = rb * 16 + srow;            // covers all NT rows
            gl_lds16(Bw + (size_t)(nblk + row) * K + k0 + kh * 32 + spart * 8,
                     Bl[buf] + kh * (NT * 32) + rb * 512);
        }
    };

    const int niter = (kend - kbeg) >> 6;
    stage(0, kbeg);                  // prologue batch stays in flight into iter 0
    int cur = 0;

    for (int it = 0; it < niter; ++it) {
        int k0 = kbeg + (it << 6);
        if (it + 1 < niter) {
            stage(cur ^ 1, k0 + 64);             // issue next tile (+LPW in flight)
            if constexpr (LPW == 8) asm volatile("s_waitcnt vmcnt(8)" ::: "memory");
            else                    asm volatile("s_waitcnt vmcnt(6)" ::: "memory");
        } else {
            asm volatile("s_waitcnt vmcnt(0)" ::: "memory");
        }
        __builtin_amdgcn_sched_barrier(0);
        __builtin_amdgcn_s_barrier();            // all waves: cur's LDS writes done
        __builtin_amdgcn_sched_barrier(0);

        #pragma unroll
        for (int kh = 0; kh < 2; ++kh) {
            bf16x8 af[4], bfr[NTW];
            #pragma unroll
            for (int mt = 0; mt < 4; ++mt)
                af[mt] = *(const bf16x8*)(Al[cur] + kh * 4096 + (wm * 64 + mt * 16 + ln) * 32 + q * 8);
            #pragma unroll
            for (int nt = 0; nt < NTW; ++nt)
                bfr[nt] = *(const bf16x8*)(Bl[cur] + kh * (NT * 32) + (wn * (NT/2) + nt * 16 + ln) * 32 + q * 8);
            #pragma unroll
            for (int mt = 0; mt < 4; ++mt)
                #pragma unroll
                for (int nt = 0; nt < NTW; ++nt)
                    acc[mt][nt] = __builtin_amdgcn_mfma_f32_16x16x32_bf16(
                        af[mt], bfr[nt], acc[mt][nt], 0, 0, 0);
        }

        __builtin_amdgcn_sched_barrier(0);
        __builtin_amdgcn_s_barrier();            // reads of buf[cur] done everywhere
        cur ^= 1;
    }

    size_t cofs = SPLITK2 ? (size_t)blockIdx.z * M * N : 0;
    #pragma unroll
    for (int mt = 0; mt < 4; ++mt) {
        #pragma unroll
        for (int nt = 0; nt < NTW; ++nt) {
            int col = nblk + wn * (NT/2) + nt * 16 + ln;
            #pragma unroll
            for (int r = 0; r < 4; ++r) {
                int row = mblk + wm * 64 + mt * 16 + q * 4 + r;
                if (OUT_BF16)
                    ((unsigned short*)Cv)[cofs + (size_t)row * N + col] = f2bf(acc[mt][nt][r]);
                else
                    ((float*)Cv)[cofs + (size_t)row * N + col] = acc[mt][nt][r];
            }
        }
    }
}

// gemm2 split-K reduce: out = p0 + p1 + bias
__global__ void splitk_reduce_kernel(const float* __restrict__ part,
                                     const float* __restrict__ bias,
                                     float* __restrict__ out) {
    int i = (blockIdx.x * 256 + threadIdx.x) * 4;   // over 2048*1024
    int n = i & (D_MODEL - 1);
    float4 a = *(const float4*)(part + i);
    float4 b = *(const float4*)(part + (size_t)MROWS * D_MODEL + i);
    float4 bv = *(const float4*)(bias + n);
    float4 o;
    o.x = a.x + b.x + bv.x; o.y = a.y + b.y + bv.y;
    o.z = a.z + b.z + bv.z; o.w = a.w + b.w + bv.w;
    *(float4*)(out + i) = o;
}

// ---------------- fused causal conv(k=4)+silu -> ub, AND xproj dots ------------
// R7 (kept; measured net win): block = one row m. Each thread computes 8
// channels of conv+silu (fp32 u in regs), stores ub bf16, then the 17 xproj
// dot partials from its OWN registers, shfl-tree wave reduce, LDS combine.
__global__ void conv_xproj_kernel(const unsigned short* __restrict__ xzb,
                                  const float* __restrict__ conv_w,
                                  const unsigned short* __restrict__ wbp,
                                  unsigned short* __restrict__ ub,
                                  float* __restrict__ dti,
                                  float* __restrict__ Bm) {
    __shared__ float red[4][17];
    const int tid = threadIdx.x;
    const int m = blockIdx.x;
    const int l = m & (SEQ - 1);
    const int d = tid * 8;
    const int lane = tid & 63;
    const int wid  = tid >> 6;

    // conv + silu
    const float4* wv = (const float4*)(conv_w + (size_t)d * 4);
    float4 w[8];
    #pragma unroll
    for (int e = 0; e < 8; ++e) w[e] = wv[e];
    float s[8] = {0.f, 0.f, 0.f, 0.f, 0.f, 0.f, 0.f, 0.f};
    #pragma unroll
    for (int j = 0; j < 4; ++j) {
        if (l - j >= 0) {
            u16x8 r = *(const u16x8*)(xzb + (size_t)(m - j) * 4096 + d);
            #pragma unroll
            for (int e = 0; e < 8; ++e) {
                float wt = (j == 0) ? w[e].w : (j == 1) ? w[e].z
                         : (j == 2) ? w[e].y : w[e].x;     // w[3-j]
                s[e] += wt * bf2f(r[e]);
            }
        }
    }
    float u[8];
    u16x8 o;
    #pragma unroll
    for (int e = 0; e < 8; ++e) {
        float sig = 1.f / (1.f + __expf(-s[e]));
        u[e] = s[e] * sig;
        o[e] = f2bf(u[e]);
    }
    *(u16x8*)(ub + (size_t)m * D_INNER + d) = o;

    // xproj: x_dbl[m,n] = sum_d u[m,d]*wbp[n,d], n in [0,17)
    #pragma unroll
    for (int n = 0; n < 17; ++n) {
        u16x8 wn = *(const u16x8*)(wbp + (size_t)n * D_INNER + d);
        float p = 0.f;
        #pragma unroll
        for (int e = 0; e < 8; ++e) p += u[e] * bf2f(wn[e]);
        #pragma unroll
        for (int off = 32; off > 0; off >>= 1)
            p += __shfl_xor(p, off, 64);
        if (lane == 0) red[wid][n] = p;
    }
    __syncthreads();
    if (tid < 17) {
        float ssum = red[0][tid] + red[1][tid] + red[2][tid] + red[3][tid];
        if (tid == 0) dti[m] = ssum;
        else Bm[(size_t)m * D_STATE + (tid - 1)] = ssum;
    }
}

// ---------------- chunked selective scan ---------------------------------------
// R8: D_STATE split across 2 threads (8 states each). Block covers DPB=128
// channels x 2 halves. 16x32x2 = 1024 blocks -> 16 waves/CU (was 4).
__device__ __forceinline__ float softplus_f(float xv) {
    return fmaxf(xv, 0.f) + __logf(1.f + __expf(-fabsf(xv)));
}

__global__ void scanA_kernel(const float* __restrict__ dt_in,
                             const float* __restrict__ Bm,
                             const float* __restrict__ dt_w,
                             const float* __restrict__ dt_b,
                             const float* __restrict__ A_param,
                             float* __restrict__ Pg,
                             float* __restrict__ Sg) {
    __shared__ float sdt[TCH];
    __shared__ float sB[TCH * D_STATE];
    const int tid = threadIdx.x;
    const int b = blockIdx.z, c = blockIdx.y;
    const int ch = tid >> 1, half = tid & 1;
    const int d = blockIdx.x * DPB + ch;

    if (tid < TCH) sdt[tid] = dt_in[b * SEQ + c * TCH + tid];
    if (tid < TCH * D_STATE / 4)
        ((float4*)sB)[tid] = ((const float4*)(Bm + ((size_t)(b * SEQ + c * TCH)) * D_STATE))[tid];
    __syncthreads();

    const float dtw = dt_w[d], dtb = dt_b[d];
    float aA[8], h[8];
    #pragma unroll
    for (int n4 = 0; n4 < 2; ++n4) {
        float4 ap = ((const float4*)(A_param + (size_t)d * D_STATE + half * 8))[n4];
        aA[n4*4+0] = -__expf(ap.x); aA[n4*4+1] = -__expf(ap.y);
        aA[n4*4+2] = -__expf(ap.z); aA[n4*4+3] = -__expf(ap.w);
    }
    #pragma unroll
    for (int n = 0; n < 8; ++n) h[n] = 0.f;
    float tsum = 0.f;

    for (int t = 0; t < TCH; ++t) {
        float sp = softplus_f(sdt[t] * dtw + dtb);
        tsum += sp;
        const float* Bt = sB + t * D_STATE + half * 8;
        #pragma unroll
        for (int n = 0; n < 8; ++n) {
            float a = __expf(aA[n] * sp);
            h[n] = a * h[n] + sp * Bt[n];
        }
    }

    size_t base = (size_t)c * NREC + ((size_t)(b * D_INNER + d)) * D_STATE + half * 8;
    #pragma unroll
    for (int n4 = 0; n4 < 2; ++n4) {
        float4 pv, sv;
        pv.x = __expf(aA[n4*4+0] * tsum); pv.y = __expf(aA[n4*4+1] * tsum);
        pv.z = __expf(aA[n4*4+2] * tsum); pv.w = __expf(aA[n4*4+3] * tsum);
        sv.x = h[n4*4+0]; sv.y = h[n4*4+1]; sv.z = h[n4*4+2]; sv.w = h[n4*4+3];
        *(float4*)(Pg + base + n4 * 4) = pv;
        *(float4*)(Sg + base + n4 * 4) = sv;
    }
}

__global__ void scanB_kernel(const float* __restrict__ Pg,
                             const float* __restrict__ Sg,
                             float* __restrict__ Hin) {
    int idx = blockIdx.x * 256 + threadIdx.x;
    float h = 0.f;
    #pragma unroll
    for (int c = 0; c < NCH; ++c) {
        size_t o = (size_t)c * NREC + idx;
        Hin[o] = h;
        h = Pg[o] * h + Sg[o];
    }
}

// scanC fused with ypost: yp[m,d] = (y + u*D) * silu(z) -> bf16
// R8: state-split x2; y combined via one shfl_xor; even lane stores.
__global__ void scanC_kernel(const float* __restrict__ dt_in,
                             const float* __restrict__ Bm,
                             const float* __restrict__ dt_w,
                             const float* __restrict__ dt_b,
                             const float* __restrict__ A_param,
                             const float* __restrict__ Hin,
                             const unsigned short* __restrict__ ub,
                             const unsigned short* __restrict__ xzb,
                             const float* __restrict__ Dp,
                             unsigned short* __restrict__ ypb) {
    __shared__ float sdt[TCH];
    __shared__ float sB[TCH * D_STATE];
    const int tid = threadIdx.x;
    const int b = blockIdx.z, c = blockIdx.y;
    const int ch = tid >> 1, half = tid & 1;
    const int d = blockIdx.x * DPB + ch;

    if (tid < TCH) sdt[tid] = dt_in[b * SEQ + c * TCH + tid];
    if (tid < TCH * D_STATE / 4)
        ((float4*)sB)[tid] = ((const float4*)(Bm + ((size_t)(b * SEQ + c * TCH)) * D_STATE))[tid];
    __syncthreads();

    const float dtw = dt_w[d], dtb = dt_b[d];
    const float Dv = Dp[d];
    float aA[8], h[8];
    #pragma unroll
    for (int n4 = 0; n4 < 2; ++n4) {
        float4 ap = ((const float4*)(A_param + (size_t)d * D_STATE + half * 8))[n4];
        aA[n4*4+0] = -__expf(ap.x); aA[n4*4+1] = -__expf(ap.y);
        aA[n4*4+2] = -__expf(ap.z); aA[n4*4+3] = -__expf(ap.w);
    }
    size_t hbase = (size_t)c * NREC + ((size_t)(b * D_INNER + d)) * D_STATE + half * 8;
    #pragma unroll
    for (int n4 = 0; n4 < 2; ++n4) {
        float4 hv = *(const float4*)(Hin + hbase + n4 * 4);
        h[n4*4+0] = hv.x; h[n4*4+1] = hv.y; h[n4*4+2] = hv.z; h[n4*4+3] = hv.w;
    }

    const size_t mrow0 = (size_t)b * SEQ + c * TCH;
    for (int t = 0; t < TCH; ++t) {
        float sp = softplus_f(sdt[t] * dtw + dtb);
        const float* Bt = sB + t * D_STATE + half * 8;
        float y0 = 0.f, y1 = 0.f;
        #pragma unroll
        for (int n4 = 0; n4 < 2; ++n4) {
            #pragma unroll
            for (int j = 0; j < 4; ++j) {
                int n = n4 * 4 + j;
                float Bv = Bt[n];
                float a = __expf(aA[n] * sp);
                h[n] = a * h[n] + sp * Bv;
                float p = h[n] * Bv;
                if (n4 == 0) y0 += p; else y1 += p;
            }
        }
        float y = y0 + y1;
        y += __shfl_xor(y, 1, 64);          // combine the two state-halves
        if (half == 0) {
            size_t m = mrow0 + t;
            float z  = bf2f(xzb[m * 4096 + D_INNER + d]);
            float sz = z / (1.f + __expf(-z));
            float uv = bf2f(ub[m * D_INNER + d]);
            ypb[m * D_INNER + d] = f2bf((y + uv * Dv) * sz);
        }
    }
}

// ---------------- launch -------------------------------------------------------
extern "C" void kernel_launch(void* const* d_in, const int* in_sizes, int n_in,
                              void* d_out, int out_size, void* d_ws, size_t ws_size,
                              hipStream_t stream) {
    const float* x         = (const float*)d_in[0];
    const float* in_proj_w = (const float*)d_in[1];
    const float* conv_w    = (const float*)d_in[2];
    const float* x_proj_w  = (const float*)d_in[3];
    const float* dt_w      = (const float*)d_in[4];
    const float* dt_b      = (const float*)d_in[5];
    const float* A_param   = (const float*)d_in[6];
    const float* D_param   = (const float*)d_in[7];
    const float* out_w     = (const float*)d_in[8];
    const float* out_b     = (const float*)d_in[9];
    float* out = (float*)d_out;

    // workspace layout — all regions disjoint (92 MB)
    char* ws = (char*)d_ws;
    unsigned short* xb  = (unsigned short*)(ws);                      //  4 MB
    unsigned short* wbi = (unsigned short*)(ws + (4u  << 20));        //  8 MB
    unsigned short* wbo = (unsigned short*)(ws + (12u << 20));        //  4 MB
    unsigned short* xzb = (unsigned short*)(ws + (16u << 20));        // 16 MB (bf16)
    unsigned short* ub  = (unsigned short*)(ws + (32u << 20));        //  8 MB
    float*          dti = (float*)(ws + (40u << 20));                 //  8 KB
    float*          Bm  = (float*)(ws + (40u << 20) + (64u  << 10));  // 128 KB
    unsigned short* wbp = (unsigned short*)(ws + (40u << 20) + (192u << 10)); // 128 KB
    float*          Pg  = (float*)(ws + (44u << 20));                 //  8 MB
    float*          Sg  = (float*)(ws + (52u << 20));                 //  8 MB
    float*          Hin = (float*)(ws + (60u << 20));                 //  8 MB
    unsigned short* ypb = (unsigned short*)(ws + (68u << 20));        //  8 MB
    float*          g2p = (float*)(ws + (76u << 20));                 // 16 MB partials

    // 1) fp32 -> bf16 conversions
    cvt_all_kernel<<<dim3(8448), 256, 0, stream>>>(
        x, in_proj_w, out_w, x_proj_w, xb, wbi, wbo, wbp);

    // 2) xz = x @ in_proj_w^T -> bf16 (M=2048, N=4096, K=1024), 512 blocks
    gemm_bf16_kernel<128, false, true><<<dim3(4096 / 128, MROWS / 128), 256, 0, stream>>>(
        xb, wbi, xzb, MROWS, 2 * D_INNER, D_MODEL);

    // 3) u = silu(causal_conv(xz[:, :2048])) -> bf16, fused with xproj dots
    conv_xproj_kernel<<<dim3(MROWS), 256, 0, stream>>>(xzb, conv_w, wbp, ub, dti, Bm);

    // 4) chunked selective scan (state-split x2); scanC fuses gate -> ypb (bf16)
    scanA_kernel<<<dim3(D_INNER / DPB, NCH, BATCH), 256, 0, stream>>>(
        dti, Bm, dt_w, dt_b, A_param, Pg, Sg);
    scanB_kernel<<<dim3(NREC / 256), 256, 0, stream>>>(Pg, Sg, Hin);
    scanC_kernel<<<dim3(D_INNER / DPB, NCH, BATCH), 256, 0, stream>>>(
        dti, Bm, dt_w, dt_b, A_param, Hin, ub, xzb, D_param, ypb);

    // 5) out partials = yp @ out_w^T (M=2048, N=1024, K=2048 split 2), 512 blocks
    gemm_bf16_kernel<64, true, false><<<dim3(1024 / 64, MROWS / 128, 2), 256, 0, stream>>>(
        ypb, wbo, g2p, MROWS, D_MODEL, D_INNER);

    // 6) out = p0 + p1 + out_b
    splitk_reduce_kernel<<<dim3(MROWS * D_MODEL / 1024), 256, 0, stream>>>(g2p, out_b, out);
}

// Round 5
// 223.455 us; speedup vs baseline: 1.0117x; 1.0117x over previous
//
#include <hip/hip_runtime.h>
#include <stdint.h>
#include <stddef.h>

#define D_MODEL 1024
#define D_STATE 16
#define D_INNER 2048
#define BATCH   2
#define SEQ     1024
#define MROWS   (BATCH*SEQ)   // 2048

// chunked scan config — R10: reverted to R1's non-split NCH=32 scan (bisect:
// R3's state-split x2 is the suspected +5.6us regression; conv_xproj kept).
#define NCH 32
#define TCH (SEQ/NCH)         // 32
#define NREC (BATCH*D_INNER*D_STATE)  // 65536

typedef __bf16 bf16x8 __attribute__((ext_vector_type(8)));
typedef float  f32x4  __attribute__((ext_vector_type(4)));
typedef unsigned short u16x8 __attribute__((ext_vector_type(8)));

__device__ __forceinline__ unsigned short f2bf(float f) {
    unsigned int u = __float_as_uint(f);
    u += 0x7fffu + ((u >> 16) & 1u);      // RNE
    return (unsigned short)(u >> 16);
}
__device__ __forceinline__ float bf2f(unsigned short v) {
    return __uint_as_float((unsigned int)v << 16);
}

// async global -> LDS, 16B/lane. Global addr is PER-LANE (gather); LDS dest is
// wave-uniform base + lane*16 (m104/m108).
__device__ __forceinline__ void gl_lds16(const unsigned short* g, unsigned short* l) {
    __builtin_amdgcn_global_load_lds(
        (const __attribute__((address_space(1))) unsigned int*)g,
        (__attribute__((address_space(3))) unsigned int*)l, 16, 0, 0);
}

// ---------------- fused fp32 -> bf16 conversions -------------------------------
__global__ void cvt_all_kernel(const float* __restrict__ x,
                               const float* __restrict__ w1,
                               const float* __restrict__ w2,
                               const float* __restrict__ xw,
                               unsigned short* __restrict__ xb,
                               unsigned short* __restrict__ wbi,
                               unsigned short* __restrict__ wbo,
                               unsigned short* __restrict__ wbp) {
    int blk = blockIdx.x, tid = threadIdx.x;
    if (blk < 8192) {
        const float* src; unsigned short* dst; int i;
        if (blk < 2048)      { src = x;  dst = xb;  i = blk * 1024 + tid * 4; }
        else if (blk < 6144) { src = w1; dst = wbi; i = (blk - 2048) * 1024 + tid * 4; }
        else                 { src = w2; dst = wbo; i = (blk - 6144) * 1024 + tid * 4; }
        float4 v = *(const float4*)(src + i);
        ushort4 o;
        o.x = f2bf(v.x); o.y = f2bf(v.y); o.z = f2bf(v.z); o.w = f2bf(v.w);
        *(ushort4*)(dst + i) = o;
    } else {
        int id = (blk - 8192) * 256 + tid;          // 0..65535
        wbp[id] = (id < 17 * D_INNER) ? f2bf(xw[id]) : (unsigned short)0;
    }
}

// ---------------- bf16 MFMA GEMM, BK=64 dual-panel LDS -------------------------
// C[m,n] = sum_k A[m,k]*Bw[n,k]. Tile 128 x NT, 256 thr (4 waves 2x2).
// R9 counted-vmcnt pipeline (measured neutral vs R3 — kept; source-level GEMM
// pipelining at this structure/shape is closed per R1/R4 nulls).
// SPLITK2: gridDim.z==2, each z does K/2, C holds partials [z][M][N].
template<int NT, bool SPLITK2, bool OUT_BF16>
__global__ void gemm_bf16_kernel(const unsigned short* __restrict__ A,
                                 const unsigned short* __restrict__ Bw,
                                 void* __restrict__ Cv,
                                 int M, int N, int K) {
    constexpr int NTW = NT / 32;                 // n-frags per wave (4 or 2)
    constexpr int BCH = NT / 8;                  // B chunks per k-iter (16 or 8)
    constexpr int LPW = 4 + BCH / 4;             // gl_lds per wave per stage (8 or 6)
    __shared__ __align__(16) unsigned short Al[2][2 * 128 * 32];   // 2 x 16 KB
    __shared__ __align__(16) unsigned short Bl[2][2 * NT * 32];

    const int tid  = threadIdx.x;
    const int lane = tid & 63;
    const int wid  = tid >> 6;
    const int wm   = wid >> 1;
    const int wn   = wid & 1;
    const int ln   = lane & 15;
    const int q    = lane >> 4;
    const int mblk = blockIdx.y * 128;
    const int nblk = blockIdx.x * NT;
    const int srow = lane >> 2;                  // 0..15 rows within chunk
    const int spart = lane & 3;                  // 16B part within 64B k-half

    const int kbeg = SPLITK2 ? blockIdx.z * (K / 2) : 0;
    const int kend = SPLITK2 ? kbeg + K / 2 : K;

    f32x4 acc[4][NTW] = {};

    auto stage = [&](int buf, int k0) {
        #pragma unroll
        for (int h = 0; h < 4; ++h) {
            int j = wid * 4 + h;
            int kh = j & 1, rb = j >> 1;
            int row = rb * 16 + srow;
            gl_lds16(A + (size_t)(mblk + row) * K + k0 + kh * 32 + spart * 8,
                     Al[buf] + kh * 4096 + rb * 512);
        }
        #pragma unroll
        for (int h = 0; h < BCH / 4; ++h) {
            int j = wid * (BCH / 4) + h;
            int kh = j & 1, rb = j >> 1;         // rb in [0, NT/16)
            int row = rb * 16 + srow;            // covers all NT rows
            gl_lds16(Bw + (size_t)(nblk + row) * K + k0 + kh * 32 + spart * 8,
                     Bl[buf] + kh * (NT * 32) + rb * 512);
        }
    };

    const int niter = (kend - kbeg) >> 6;
    stage(0, kbeg);                  // prologue batch stays in flight into iter 0
    int cur = 0;

    for (int it = 0; it < niter; ++it) {
        int k0 = kbeg + (it << 6);
        if (it + 1 < niter) {
            stage(cur ^ 1, k0 + 64);             // issue next tile (+LPW in flight)
            if constexpr (LPW == 8) asm volatile("s_waitcnt vmcnt(8)" ::: "memory");
            else                    asm volatile("s_waitcnt vmcnt(6)" ::: "memory");
        } else {
            asm volatile("s_waitcnt vmcnt(0)" ::: "memory");
        }
        __builtin_amdgcn_sched_barrier(0);
        __builtin_amdgcn_s_barrier();            // all waves: cur's LDS writes done
        __builtin_amdgcn_sched_barrier(0);

        #pragma unroll
        for (int kh = 0; kh < 2; ++kh) {
            bf16x8 af[4], bfr[NTW];
            #pragma unroll
            for (int mt = 0; mt < 4; ++mt)
                af[mt] = *(const bf16x8*)(Al[cur] + kh * 4096 + (wm * 64 + mt * 16 + ln) * 32 + q * 8);
            #pragma unroll
            for (int nt = 0; nt < NTW; ++nt)
                bfr[nt] = *(const bf16x8*)(Bl[cur] + kh * (NT * 32) + (wn * (NT/2) + nt * 16 + ln) * 32 + q * 8);
            #pragma unroll
            for (int mt = 0; mt < 4; ++mt)
                #pragma unroll
                for (int nt = 0; nt < NTW; ++nt)
                    acc[mt][nt] = __builtin_amdgcn_mfma_f32_16x16x32_bf16(
                        af[mt], bfr[nt], acc[mt][nt], 0, 0, 0);
        }

        __builtin_amdgcn_sched_barrier(0);
        __builtin_amdgcn_s_barrier();            // reads of buf[cur] done everywhere
        cur ^= 1;
    }

    size_t cofs = SPLITK2 ? (size_t)blockIdx.z * M * N : 0;
    #pragma unroll
    for (int mt = 0; mt < 4; ++mt) {
        #pragma unroll
        for (int nt = 0; nt < NTW; ++nt) {
            int col = nblk + wn * (NT/2) + nt * 16 + ln;
            #pragma unroll
            for (int r = 0; r < 4; ++r) {
                int row = mblk + wm * 64 + mt * 16 + q * 4 + r;
                if (OUT_BF16)
                    ((unsigned short*)Cv)[cofs + (size_t)row * N + col] = f2bf(acc[mt][nt][r]);
                else
                    ((float*)Cv)[cofs + (size_t)row * N + col] = acc[mt][nt][r];
            }
        }
    }
}

// gemm2 split-K reduce: out = p0 + p1 + bias
__global__ void splitk_reduce_kernel(const float* __restrict__ part,
                                     const float* __restrict__ bias,
                                     float* __restrict__ out) {
    int i = (blockIdx.x * 256 + threadIdx.x) * 4;   // over 2048*1024
    int n = i & (D_MODEL - 1);
    float4 a = *(const float4*)(part + i);
    float4 b = *(const float4*)(part + (size_t)MROWS * D_MODEL + i);
    float4 bv = *(const float4*)(bias + n);
    float4 o;
    o.x = a.x + b.x + bv.x; o.y = a.y + b.y + bv.y;
    o.z = a.z + b.z + bv.z; o.w = a.w + b.w + bv.w;
    *(float4*)(out + i) = o;
}

// ---------------- fused causal conv(k=4)+silu -> ub, AND xproj dots ------------
// R7 (kept this round; bisect targets the scan): block = one row m. Each thread
// computes 8 channels of conv+silu (fp32 u in regs), stores ub bf16, then the
// 17 xproj dot partials from its OWN registers, shfl-tree wave reduce, LDS
// combine. Replaces xproj_mfma + xproj_reduce kernels.
__global__ void conv_xproj_kernel(const unsigned short* __restrict__ xzb,
                                  const float* __restrict__ conv_w,
                                  const unsigned short* __restrict__ wbp,
                                  unsigned short* __restrict__ ub,
                                  float* __restrict__ dti,
                                  float* __restrict__ Bm) {
    __shared__ float red[4][17];
    const int tid = threadIdx.x;
    const int m = blockIdx.x;
    const int l = m & (SEQ - 1);
    const int d = tid * 8;
    const int lane = tid & 63;
    const int wid  = tid >> 6;

    // conv + silu
    const float4* wv = (const float4*)(conv_w + (size_t)d * 4);
    float4 w[8];
    #pragma unroll
    for (int e = 0; e < 8; ++e) w[e] = wv[e];
    float s[8] = {0.f, 0.f, 0.f, 0.f, 0.f, 0.f, 0.f, 0.f};
    #pragma unroll
    for (int j = 0; j < 4; ++j) {
        if (l - j >= 0) {
            u16x8 r = *(const u16x8*)(xzb + (size_t)(m - j) * 4096 + d);
            #pragma unroll
            for (int e = 0; e < 8; ++e) {
                float wt = (j == 0) ? w[e].w : (j == 1) ? w[e].z
                         : (j == 2) ? w[e].y : w[e].x;     // w[3-j]
                s[e] += wt * bf2f(r[e]);
            }
        }
    }
    float u[8];
    u16x8 o;
    #pragma unroll
    for (int e = 0; e < 8; ++e) {
        float sig = 1.f / (1.f + __expf(-s[e]));
        u[e] = s[e] * sig;
        o[e] = f2bf(u[e]);
    }
    *(u16x8*)(ub + (size_t)m * D_INNER + d) = o;

    // xproj: x_dbl[m,n] = sum_d u[m,d]*wbp[n,d], n in [0,17)
    #pragma unroll
    for (int n = 0; n < 17; ++n) {
        u16x8 wn = *(const u16x8*)(wbp + (size_t)n * D_INNER + d);
        float p = 0.f;
        #pragma unroll
        for (int e = 0; e < 8; ++e) p += u[e] * bf2f(wn[e]);
        #pragma unroll
        for (int off = 32; off > 0; off >>= 1)
            p += __shfl_xor(p, off, 64);
        if (lane == 0) red[wid][n] = p;
    }
    __syncthreads();
    if (tid < 17) {
        float ssum = red[0][tid] + red[1][tid] + red[2][tid] + red[3][tid];
        if (tid == 0) dti[m] = ssum;
        else Bm[(size_t)m * D_STATE + (tid - 1)] = ssum;
    }
}

// ---------------- chunked selective scan (R1 non-split form) -------------------
__device__ __forceinline__ float softplus_f(float xv) {
    return fmaxf(xv, 0.f) + __logf(1.f + __expf(-fabsf(xv)));
}

__global__ void scanA_kernel(const float* __restrict__ dt_in,
                             const float* __restrict__ Bm,
                             const float* __restrict__ dt_w,
                             const float* __restrict__ dt_b,
                             const float* __restrict__ A_param,
                             float* __restrict__ Pg,
                             float* __restrict__ Sg) {
    __shared__ float sdt[TCH];
    __shared__ float sB[TCH * D_STATE];
    const int tid = threadIdx.x;
    const int b = blockIdx.z, c = blockIdx.y;
    const int d = blockIdx.x * 256 + tid;

    if (tid < TCH) sdt[tid] = dt_in[b * SEQ + c * TCH + tid];
    if (tid < TCH * D_STATE / 4)
        ((float4*)sB)[tid] = ((const float4*)(Bm + ((size_t)(b * SEQ + c * TCH)) * D_STATE))[tid];
    __syncthreads();

    const float dtw = dt_w[d], dtb = dt_b[d];
    float aA[D_STATE], h[D_STATE];
    #pragma unroll
    for (int n4 = 0; n4 < 4; ++n4) {
        float4 ap = ((const float4*)(A_param + (size_t)d * D_STATE))[n4];
        aA[n4*4+0] = -__expf(ap.x); aA[n4*4+1] = -__expf(ap.y);
        aA[n4*4+2] = -__expf(ap.z); aA[n4*4+3] = -__expf(ap.w);
    }
    #pragma unroll
    for (int n = 0; n < D_STATE; ++n) h[n] = 0.f;
    float tsum = 0.f;

    for (int t = 0; t < TCH; ++t) {
        float sp = softplus_f(sdt[t] * dtw + dtb);
        tsum += sp;
        #pragma unroll
        for (int n = 0; n < D_STATE; ++n) {
            float a = __expf(aA[n] * sp);
            h[n] = a * h[n] + sp * sB[t * D_STATE + n];
        }
    }

    size_t base = (size_t)c * NREC + ((size_t)(b * D_INNER + d)) * D_STATE;
    #pragma unroll
    for (int n4 = 0; n4 < 4; ++n4) {
        float4 pv, sv;
        pv.x = __expf(aA[n4*4+0] * tsum); pv.y = __expf(aA[n4*4+1] * tsum);
        pv.z = __expf(aA[n4*4+2] * tsum); pv.w = __expf(aA[n4*4+3] * tsum);
        sv.x = h[n4*4+0]; sv.y = h[n4*4+1]; sv.z = h[n4*4+2]; sv.w = h[n4*4+3];
        *(float4*)(Pg + base + n4 * 4) = pv;
        *(float4*)(Sg + base + n4 * 4) = sv;
    }
}

__global__ void scanB_kernel(const float* __restrict__ Pg,
                             const float* __restrict__ Sg,
                             float* __restrict__ Hin) {
    int idx = blockIdx.x * 256 + threadIdx.x;
    float h = 0.f;
    #pragma unroll
    for (int c = 0; c < NCH; ++c) {
        size_t o = (size_t)c * NREC + idx;
        Hin[o] = h;
        h = Pg[o] * h + Sg[o];
    }
}

// scanC fused with ypost: yp[m,d] = (y + u*D) * silu(z) -> bf16
__global__ void scanC_kernel(const float* __restrict__ dt_in,
                             const float* __restrict__ Bm,
                             const float* __restrict__ dt_w,
                             const float* __restrict__ dt_b,
                             const float* __restrict__ A_param,
                             const float* __restrict__ Hin,
                             const unsigned short* __restrict__ ub,
                             const unsigned short* __restrict__ xzb,
                             const float* __restrict__ Dp,
                             unsigned short* __restrict__ ypb) {
    __shared__ float sdt[TCH];
    __shared__ float sB[TCH * D_STATE];
    const int tid = threadIdx.x;
    const int b = blockIdx.z, c = blockIdx.y;
    const int d = blockIdx.x * 256 + tid;

    if (tid < TCH) sdt[tid] = dt_in[b * SEQ + c * TCH + tid];
    if (tid < TCH * D_STATE / 4)
        ((float4*)sB)[tid] = ((const float4*)(Bm + ((size_t)(b * SEQ + c * TCH)) * D_STATE))[tid];
    __syncthreads();

    const float dtw = dt_w[d], dtb = dt_b[d];
    const float Dv = Dp[d];
    float aA[D_STATE], h[D_STATE];
    #pragma unroll
    for (int n4 = 0; n4 < 4; ++n4) {
        float4 ap = ((const float4*)(A_param + (size_t)d * D_STATE))[n4];
        aA[n4*4+0] = -__expf(ap.x); aA[n4*4+1] = -__expf(ap.y);
        aA[n4*4+2] = -__expf(ap.z); aA[n4*4+3] = -__expf(ap.w);
    }
    size_t hbase = (size_t)c * NREC + ((size_t)(b * D_INNER + d)) * D_STATE;
    #pragma unroll
    for (int n4 = 0; n4 < 4; ++n4) {
        float4 hv = *(const float4*)(Hin + hbase + n4 * 4);
        h[n4*4+0] = hv.x; h[n4*4+1] = hv.y; h[n4*4+2] = hv.z; h[n4*4+3] = hv.w;
    }

    const size_t mrow0 = (size_t)b * SEQ + c * TCH;
    for (int t = 0; t < TCH; ++t) {
        float sp = softplus_f(sdt[t] * dtw + dtb);
        float y0 = 0.f, y1 = 0.f, y2 = 0.f, y3 = 0.f;
        #pragma unroll
        for (int n4 = 0; n4 < 4; ++n4) {
            #pragma unroll
            for (int j = 0; j < 4; ++j) {
                int n = n4 * 4 + j;
                float Bv = sB[t * D_STATE + n];
                float a = __expf(aA[n] * sp);
                h[n] = a * h[n] + sp * Bv;
                float p = h[n] * Bv;
                if (n4 == 0) y0 += p; else if (n4 == 1) y1 += p;
                else if (n4 == 2) y2 += p; else y3 += p;
            }
        }
        float y = (y0 + y1) + (y2 + y3);
        size_t m = mrow0 + t;
        float z  = bf2f(xzb[m * 4096 + D_INNER + d]);
        float sz = z / (1.f + __expf(-z));
        float uv = bf2f(ub[m * D_INNER + d]);
        ypb[m * D_INNER + d] = f2bf((y + uv * Dv) * sz);
    }
}

// ---------------- launch -------------------------------------------------------
extern "C" void kernel_launch(void* const* d_in, const int* in_sizes, int n_in,
                              void* d_out, int out_size, void* d_ws, size_t ws_size,
                              hipStream_t stream) {
    const float* x         = (const float*)d_in[0];
    const float* in_proj_w = (const float*)d_in[1];
    const float* conv_w    = (const float*)d_in[2];
    const float* x_proj_w  = (const float*)d_in[3];
    const float* dt_w      = (const float*)d_in[4];
    const float* dt_b      = (const float*)d_in[5];
    const float* A_param   = (const float*)d_in[6];
    const float* D_param   = (const float*)d_in[7];
    const float* out_w     = (const float*)d_in[8];
    const float* out_b     = (const float*)d_in[9];
    float* out = (float*)d_out;

    // workspace layout — all regions disjoint (92 MB)
    char* ws = (char*)d_ws;
    unsigned short* xb  = (unsigned short*)(ws);                      //  4 MB
    unsigned short* wbi = (unsigned short*)(ws + (4u  << 20));        //  8 MB
    unsigned short* wbo = (unsigned short*)(ws + (12u << 20));        //  4 MB
    unsigned short* xzb = (unsigned short*)(ws + (16u << 20));        // 16 MB (bf16)
    unsigned short* ub  = (unsigned short*)(ws + (32u << 20));        //  8 MB
    float*          dti = (float*)(ws + (40u << 20));                 //  8 KB
    float*          Bm  = (float*)(ws + (40u << 20) + (64u  << 10));  // 128 KB
    unsigned short* wbp = (unsigned short*)(ws + (40u << 20) + (192u << 10)); // 128 KB
    float*          Pg  = (float*)(ws + (44u << 20));                 //  8 MB
    float*          Sg  = (float*)(ws + (52u << 20));                 //  8 MB
    float*          Hin = (float*)(ws + (60u << 20));                 //  8 MB
    unsigned short* ypb = (unsigned short*)(ws + (68u << 20));        //  8 MB
    float*          g2p = (float*)(ws + (76u << 20));                 // 16 MB partials

    // 1) fp32 -> bf16 conversions
    cvt_all_kernel<<<dim3(8448), 256, 0, stream>>>(
        x, in_proj_w, out_w, x_proj_w, xb, wbi, wbo, wbp);

    // 2) xz = x @ in_proj_w^T -> bf16 (M=2048, N=4096, K=1024), 512 blocks
    gemm_bf16_kernel<128, false, true><<<dim3(4096 / 128, MROWS / 128), 256, 0, stream>>>(
        xb, wbi, xzb, MROWS, 2 * D_INNER, D_MODEL);

    // 3) u = silu(causal_conv(xz[:, :2048])) -> bf16, fused with xproj dots
    conv_xproj_kernel<<<dim3(MROWS), 256, 0, stream>>>(xzb, conv_w, wbp, ub, dti, Bm);

    // 4) chunked selective scan (R1 non-split); scanC fuses gate -> ypb (bf16)
    scanA_kernel<<<dim3(D_INNER / 256, NCH, BATCH), 256, 0, stream>>>(
        dti, Bm, dt_w, dt_b, A_param, Pg, Sg);
    scanB_kernel<<<dim3(NREC / 256), 256, 0, stream>>>(Pg, Sg, Hin);
    scanC_kernel<<<dim3(D_INNER / 256, NCH, BATCH), 256, 0, stream>>>(
        dti, Bm, dt_w, dt_b, A_param, Hin, ub, xzb, D_param, ypb);

    // 5) out partials = yp @ out_w^T (M=2048, N=1024, K=2048 split 2), 512 blocks
    gemm_bf16_kernel<64, true, false><<<dim3(1024 / 64, MROWS / 128, 2), 256, 0, stream>>>(
        ypb, wbo, g2p, MROWS, D_MODEL, D_INNER);

    // 6) out = p0 + p1 + out_b
    splitk_reduce_kernel<<<dim3(MROWS * D_MODEL / 1024), 256, 0, stream>>>(g2p, out_b, out);
}